// Round 1
// baseline (1452.698 us; speedup 1.0000x reference)
//
#include <hip/hip_runtime.h>
#include <hip/hip_bf16.h>
#include <math.h>

#define Bc 32
#define Tc 512
#define Cc 256
#define Hc 8
#define Dh 32
#define BT (Bc * Tc)
#define EPS 1e-5f

// ---------------------------------------------------------------------------
// Edge scatter: agg[dst] += x[src] over E edges, 4 channels per thread
// ---------------------------------------------------------------------------
__global__ void scatter_edges_kernel(const float* __restrict__ x,
                                     const int* __restrict__ ei,
                                     float* __restrict__ agg, int E) {
    int gid = blockIdx.x * 256 + threadIdx.x;
    int e = gid >> 6;
    if (e >= E) return;
    int c4 = (gid & 63) * 4;
    int src = ei[e];
    int dst = ei[E + e];
    const float4 val = *(const float4*)(x + (size_t)src * Cc + c4);
    float* p = agg + (size_t)dst * Cc + c4;
    atomicAdd(p + 0, val.x);
    atomicAdd(p + 1, val.y);
    atomicAdd(p + 2, val.z);
    atomicAdd(p + 3, val.w);
}

// ---------------------------------------------------------------------------
// Scatter nodes into dense batch + build integer mask
// ---------------------------------------------------------------------------
__global__ void scatter_dense_kernel(const float* __restrict__ x,
                                     const int* __restrict__ idx,
                                     float* __restrict__ xd,
                                     int* __restrict__ maskI, int N) {
    int gid = blockIdx.x * 256 + threadIdx.x;
    int i = gid >> 6;
    if (i >= N) return;
    int c4 = (gid & 63) * 4;
    int slot = idx[i];
    *(float4*)(xd + (size_t)slot * Cc + c4) = *(const float4*)(x + (size_t)i * Cc + c4);
    if (c4 == 0) maskI[slot] = 1;
}

// ---------------------------------------------------------------------------
// Generic tiled f32 GEMM: Cout = act(A@B (+ A2@B2) + bias (+ res))
//   A: M x K (optional row gather via gidx), B: K x Nc row-major
//   64x64 tile, BK=16, 256 threads, 4x4 per thread
// ---------------------------------------------------------------------------
template <bool RELU>
__global__ void gemm_kernel(const float* __restrict__ A,
                            const int* __restrict__ gidx,
                            const float* __restrict__ Bm,
                            const float* __restrict__ A2,
                            const float* __restrict__ B2,
                            const float* __restrict__ bias,
                            const float* __restrict__ res,
                            float* __restrict__ Cout,
                            int M, int K, int Nc) {
    __shared__ float As[16][64];
    __shared__ float Bs[16][64];
    int tid = threadIdx.x;
    int row0 = blockIdx.y * 64;
    int col0 = blockIdx.x * 64;
    int ty = tid >> 4;   // 0..15
    int tx = tid & 15;   // 0..15
    float acc[4][4] = {};

    int npass = (A2 != nullptr) ? 2 : 1;
    for (int pass = 0; pass < npass; ++pass) {
        const float* Ap = pass ? A2 : A;
        const float* Bp = pass ? B2 : Bm;
        for (int k0 = 0; k0 < K; k0 += 16) {
            // A tile: 64 rows x 16 cols
            {
                int r = tid >> 2;
                int c4 = (tid & 3) * 4;
                int ar = row0 + r;
                float4 val = make_float4(0.f, 0.f, 0.f, 0.f);
                if (ar < M) {
                    int arr = gidx ? gidx[ar] : ar;
                    val = *(const float4*)(Ap + (size_t)arr * K + k0 + c4);
                }
                As[c4 + 0][r] = val.x;
                As[c4 + 1][r] = val.y;
                As[c4 + 2][r] = val.z;
                As[c4 + 3][r] = val.w;
            }
            // B tile: 16 rows x 64 cols
            {
                int r = tid >> 4;
                int c4 = (tid & 15) * 4;
                *(float4*)&Bs[r][c4] = *(const float4*)(Bp + (size_t)(k0 + r) * Nc + col0 + c4);
            }
            __syncthreads();
#pragma unroll
            for (int kk = 0; kk < 16; ++kk) {
                float av[4], bv[4];
#pragma unroll
                for (int i = 0; i < 4; ++i) av[i] = As[kk][ty * 4 + i];
#pragma unroll
                for (int j = 0; j < 4; ++j) bv[j] = Bs[kk][tx * 4 + j];
#pragma unroll
                for (int i = 0; i < 4; ++i)
#pragma unroll
                    for (int j = 0; j < 4; ++j) acc[i][j] += av[i] * bv[j];
            }
            __syncthreads();
        }
    }

#pragma unroll
    for (int i = 0; i < 4; ++i) {
        int r = row0 + ty * 4 + i;
        if (r >= M) continue;
#pragma unroll
        for (int j = 0; j < 4; ++j) {
            int c = col0 + tx * 4 + j;
            float v = acc[i][j];
            if (bias) v += bias[c];
            if (res) v += res[(size_t)r * Nc + c];
            if (RELU) v = fmaxf(v, 0.f);
            Cout[(size_t)r * Nc + c] = v;
        }
    }
}

// ---------------------------------------------------------------------------
// Column stats (sum, sumsq) for BN over M rows x 256 cols
// ---------------------------------------------------------------------------
__global__ void colstats_kernel(const float* __restrict__ in,
                                float* __restrict__ stats, int M) {
    int c = threadIdx.x;  // 256
    int r0 = blockIdx.x * 64;
    int rend = min(r0 + 64, M);
    float s = 0.f, s2 = 0.f;
    for (int r = r0; r < rend; ++r) {
        float v = in[(size_t)r * Cc + c];
        s += v;
        s2 += v * v;
    }
    atomicAdd(&stats[c], s);
    atomicAdd(&stats[Cc + c], s2);
}

// ---------------------------------------------------------------------------
// BN apply: out = (add?) + g*(in-mean)*rsqrt(var+eps)+be
// ---------------------------------------------------------------------------
__global__ void bn_apply_kernel(const float* __restrict__ in,
                                float* __restrict__ out,
                                const float* __restrict__ add,
                                const float* __restrict__ g,
                                const float* __restrict__ be,
                                const float* __restrict__ stats, int M) {
    int gid = blockIdx.x * 256 + threadIdx.x;
    if (gid >= M * Cc) return;
    int c = gid & (Cc - 1);
    float invM = 1.f / (float)M;
    float mean = stats[c] * invM;
    float var = stats[Cc + c] * invM - mean * mean;
    float sc = g[c] * rsqrtf(var + EPS);
    float v = (in[gid] - mean) * sc + be[c];
    if (add) v += add[gid];
    out[gid] = v;
}

// ---------------------------------------------------------------------------
// Flash-style attention. One thread = one query row. grid = B*H*2, 256 thr.
// q,k,v layout: [B,T,H,Dh]; o layout: [B,T,C] with head-contiguous last dim.
// ---------------------------------------------------------------------------
__global__ void attn_kernel(const float* __restrict__ q,
                            const float* __restrict__ k,
                            const float* __restrict__ v,
                            const int* __restrict__ maskI,
                            float* __restrict__ o) {
    int bh = blockIdx.x >> 1;
    int qc = blockIdx.x & 1;
    int b = bh >> 3;
    int h = bh & 7;
    int qrow = qc * 256 + threadIdx.x;

    __shared__ float Ks[64][Dh];
    __shared__ float Vs[64][Dh];
    __shared__ int Ms[64];

    float qv[Dh];
    const float* qp = q + ((size_t)(b * Tc + qrow) * Hc + h) * Dh;
#pragma unroll
    for (int d = 0; d < Dh; d += 4) {
        float4 t = *(const float4*)(qp + d);
        qv[d] = t.x; qv[d + 1] = t.y; qv[d + 2] = t.z; qv[d + 3] = t.w;
    }

    float m = -1e30f, l = 0.f;
    float acc[Dh] = {};
    const float scale = 0.17677669529663687f;  // 1/sqrt(32)

    for (int k0 = 0; k0 < Tc; k0 += 64) {
        __syncthreads();
        {
            int r = threadIdx.x >> 2;
            int c8 = (threadIdx.x & 3) * 8;
            const float* kp = k + ((size_t)(b * Tc + k0 + r) * Hc + h) * Dh + c8;
            const float* vp = v + ((size_t)(b * Tc + k0 + r) * Hc + h) * Dh + c8;
            *(float4*)&Ks[r][c8] = *(const float4*)(kp);
            *(float4*)&Ks[r][c8 + 4] = *(const float4*)(kp + 4);
            *(float4*)&Vs[r][c8] = *(const float4*)(vp);
            *(float4*)&Vs[r][c8 + 4] = *(const float4*)(vp + 4);
            if (threadIdx.x < 64) Ms[threadIdx.x] = maskI[b * Tc + k0 + threadIdx.x];
        }
        __syncthreads();
        for (int j = 0; j < 64; ++j) {
            if (!Ms[j]) continue;  // uniform branch (same for all lanes)
            float s = 0.f;
#pragma unroll
            for (int d = 0; d < Dh; ++d) s += qv[d] * Ks[j][d];
            s *= scale;
            float mn = fmaxf(m, s);
            float corr = __expf(m - mn);
            float p = __expf(s - mn);
            l = l * corr + p;
#pragma unroll
            for (int d = 0; d < Dh; ++d) acc[d] = acc[d] * corr + p * Vs[j][d];
            m = mn;
        }
    }

    float inv = 1.f / l;
    float* op = o + (size_t)(b * Tc + qrow) * Cc + h * Dh;
#pragma unroll
    for (int d = 0; d < Dh; d += 4) {
        float4 t;
        t.x = acc[d] * inv; t.y = acc[d + 1] * inv;
        t.z = acc[d + 2] * inv; t.w = acc[d + 3] * inv;
        *(float4*)(op + d) = t;
    }
}

// ---------------------------------------------------------------------------
// Launch
// ---------------------------------------------------------------------------
extern "C" void kernel_launch(void* const* d_in, const int* in_sizes, int n_in,
                              void* d_out, int out_size, void* d_ws, size_t ws_size,
                              hipStream_t stream) {
    const float* x      = (const float*)d_in[0];
    const int*   ei     = (const int*)d_in[1];
    const int*   idx    = (const int*)d_in[2];
    // d_in[3] = mask (bool) — unused; reconstructed from idx
    const float* W_root = (const float*)d_in[4];
    const float* W_nbr  = (const float*)d_in[5];
    const float* b_conv = (const float*)d_in[6];
    const float* Wq     = (const float*)d_in[7];
    const float* Wk     = (const float*)d_in[8];
    const float* Wv     = (const float*)d_in[9];
    const float* bq     = (const float*)d_in[10];
    const float* bk     = (const float*)d_in[11];
    const float* bv     = (const float*)d_in[12];
    const float* Wo     = (const float*)d_in[13];
    const float* bo     = (const float*)d_in[14];
    const float* W1     = (const float*)d_in[15];
    const float* b1     = (const float*)d_in[16];
    const float* W2     = (const float*)d_in[17];
    const float* b2     = (const float*)d_in[18];
    const float* g1     = (const float*)d_in[19];
    const float* be1    = (const float*)d_in[20];
    const float* g2     = (const float*)d_in[21];
    const float* be2    = (const float*)d_in[22];
    const float* g3     = (const float*)d_in[23];
    const float* be3    = (const float*)d_in[24];

    const int N = in_sizes[0] / Cc;
    const int E = in_sizes[1] / 2;

    // Workspace layout (floats)
    float* ws = (float*)d_ws;
    float* hB    = ws;                       // N*C : h_pre -> h_local -> out1
    float* hid   = hB + (size_t)N * Cc;      // N*2C
    float* xd    = hid + (size_t)N * 2 * Cc; // BT*C
    float* qb    = xd + (size_t)BT * Cc;     // BT*C
    float* kb    = qb + (size_t)BT * Cc;     // BT*C
    float* vb    = kb + (size_t)BT * Cc;     // BT*C
    float* ao    = vb + (size_t)BT * Cc;     // BT*C attention out
    float* stats = ao + (size_t)BT * Cc;     // 6*C (3 sets of [sum, sumsq])
    int*   maskI = (int*)(stats + 6 * Cc);   // BT
    // d_out doubles as a second N*C scratch: agg -> h_attn_pre -> out2 -> final
    float* bufA = (float*)d_out;

    // ---- zero the accumulated buffers ----
    hipMemsetAsync(bufA, 0, (size_t)N * Cc * sizeof(float), stream);          // agg
    hipMemsetAsync(xd, 0, (size_t)BT * Cc * sizeof(float), stream);
    hipMemsetAsync(stats, 0, 6 * Cc * sizeof(float), stream);
    hipMemsetAsync(maskI, 0, BT * sizeof(int), stream);

    // ---- 1. agg = segment_sum(x[src], dst) ----
    {
        int threads = E * 64;
        scatter_edges_kernel<<<(threads + 255) / 256, 256, 0, stream>>>(x, ei, bufA, E);
    }

    // ---- 2. h_pre = x@W_root + agg@W_nbr + b_conv + x ----
    {
        dim3 grid(Cc / 64, (N + 63) / 64);
        gemm_kernel<false><<<grid, 256, 0, stream>>>(x, nullptr, W_root, bufA, W_nbr,
                                                     b_conv, x, hB, N, Cc, Cc);
    }
    // ---- 3. BN1 in place: hB = h_local ----
    colstats_kernel<<<(N + 63) / 64, 256, 0, stream>>>(hB, stats, N);
    bn_apply_kernel<<<N, 256, 0, stream>>>(hB, hB, nullptr, g1, be1, stats, N);

    // ---- 4. dense batch scatter + mask ----
    scatter_dense_kernel<<<(N * 64 + 255) / 256, 256, 0, stream>>>(x, idx, xd, maskI, N);

    // ---- 5. q,k,v = xd@W + b ----
    {
        dim3 grid(Cc / 64, BT / 64);
        gemm_kernel<false><<<grid, 256, 0, stream>>>(xd, nullptr, Wq, nullptr, nullptr,
                                                     bq, nullptr, qb, BT, Cc, Cc);
        gemm_kernel<false><<<grid, 256, 0, stream>>>(xd, nullptr, Wk, nullptr, nullptr,
                                                     bk, nullptr, kb, BT, Cc, Cc);
        gemm_kernel<false><<<grid, 256, 0, stream>>>(xd, nullptr, Wv, nullptr, nullptr,
                                                     bv, nullptr, vb, BT, Cc, Cc);
    }

    // ---- 6. attention -> ao [B,T,C] ----
    attn_kernel<<<Bc * Hc * 2, 256, 0, stream>>>(qb, kb, vb, maskI, ao);

    // ---- 7. h_attn_pre = ao[idx]@Wo + bo + x  (gathered unpad + residual) ----
    {
        dim3 grid(Cc / 64, (N + 63) / 64);
        gemm_kernel<false><<<grid, 256, 0, stream>>>(ao, idx, Wo, nullptr, nullptr,
                                                     bo, x, bufA, N, Cc, Cc);
    }
    // ---- 8. BN2 + combine: hB(out1) = h_local + bn(h_attn_pre) ----
    colstats_kernel<<<(N + 63) / 64, 256, 0, stream>>>(bufA, stats + 2 * Cc, N);
    bn_apply_kernel<<<N, 256, 0, stream>>>(bufA, hB, hB, g2, be2, stats + 2 * Cc, N);

    // ---- 9. hid = relu(out1@W1 + b1) ----
    {
        dim3 grid(2 * Cc / 64, (N + 63) / 64);
        gemm_kernel<true><<<grid, 256, 0, stream>>>(hB, nullptr, W1, nullptr, nullptr,
                                                    b1, nullptr, hid, N, Cc, 2 * Cc);
    }
    // ---- 10. out2 = out1 + hid@W2 + b2 ----
    {
        dim3 grid(Cc / 64, (N + 63) / 64);
        gemm_kernel<false><<<grid, 256, 0, stream>>>(hid, nullptr, W2, nullptr, nullptr,
                                                     b2, hB, bufA, N, 2 * Cc, Cc);
    }
    // ---- 11. BN3 -> d_out (in place on bufA == d_out) ----
    colstats_kernel<<<(N + 63) / 64, 256, 0, stream>>>(bufA, stats + 4 * Cc, N);
    bn_apply_kernel<<<N, 256, 0, stream>>>(bufA, bufA, nullptr, g3, be3, stats + 4 * Cc, N);
}

// Round 2
// 788.757 us; speedup vs baseline: 1.8418x; 1.8418x over previous
//
#include <hip/hip_runtime.h>
#include <hip/hip_bf16.h>
#include <math.h>

#define Bc 32
#define Tc 512
#define Cc 256
#define Hc 8
#define Dh 32
#define BT (Bc * Tc)
#define EPS 1e-5f

// ---------------------------------------------------------------------------
// CSR build: degree histogram over destination nodes
// ---------------------------------------------------------------------------
__global__ void degree_kernel(const int* __restrict__ ei, int* __restrict__ deg,
                              int E) {
    int e = blockIdx.x * 256 + threadIdx.x;
    if (e >= E) return;
    atomicAdd(&deg[ei[E + e]], 1);
}

// Single-block exclusive prefix sum over N degrees -> start offsets
__global__ void prefix_kernel(const int* __restrict__ deg, int* __restrict__ start,
                              int N) {
    __shared__ int sums[1024];
    int tid = threadIdx.x;
    int per = (N + 1023) / 1024;
    int base = tid * per;
    int s = 0;
    for (int i = 0; i < per; ++i) {
        int g = base + i;
        if (g < N) s += deg[g];
    }
    sums[tid] = s;
    __syncthreads();
    for (int off = 1; off < 1024; off <<= 1) {
        int v = (tid >= off) ? sums[tid - off] : 0;
        __syncthreads();
        sums[tid] += v;
        __syncthreads();
    }
    int run = (tid == 0) ? 0 : sums[tid - 1];
    for (int i = 0; i < per; ++i) {
        int g = base + i;
        if (g < N) { start[g] = run; run += deg[g]; }
    }
}

// Fill CSR: csr[start[dst] + pos] = src
__global__ void fill_csr_kernel(const int* __restrict__ ei,
                                const int* __restrict__ start,
                                int* __restrict__ cursor,
                                int* __restrict__ csr, int E) {
    int e = blockIdx.x * 256 + threadIdx.x;
    if (e >= E) return;
    int dst = ei[E + e];
    int pos = atomicAdd(&cursor[dst], 1);
    csr[start[dst] + pos] = ei[e];
}

// Gather-sum: one block per destination node, 256 channels
__global__ void gather_kernel(const float* __restrict__ x,
                              const int* __restrict__ csr,
                              const int* __restrict__ start,
                              const int* __restrict__ deg,
                              float* __restrict__ agg, int N) {
    int i = blockIdx.x;
    int c = threadIdx.x;
    int s0 = start[i];
    int s1 = s0 + deg[i];
    float s = 0.f;
    for (int e = s0; e < s1; ++e)
        s += x[(size_t)csr[e] * Cc + c];
    agg[(size_t)i * Cc + c] = s;
}

// ---------------------------------------------------------------------------
// Scatter nodes into dense batch + build integer mask
// ---------------------------------------------------------------------------
__global__ void scatter_dense_kernel(const float* __restrict__ x,
                                     const int* __restrict__ idx,
                                     float* __restrict__ xd,
                                     int* __restrict__ maskI, int N) {
    int gid = blockIdx.x * 256 + threadIdx.x;
    int i = gid >> 6;
    if (i >= N) return;
    int c4 = (gid & 63) * 4;
    int slot = idx[i];
    *(float4*)(xd + (size_t)slot * Cc + c4) = *(const float4*)(x + (size_t)i * Cc + c4);
    if (c4 == 0) maskI[slot] = 1;
}

// ---------------------------------------------------------------------------
// Generic tiled f32 GEMM: Cout = act(A@B (+ A2@B2) + bias (+ res))
//   A: M x K (optional row gather via gidx), B: K x Nc row-major
//   64x64 tile, BK=16, 256 threads, 4x4 per thread
// ---------------------------------------------------------------------------
template <bool RELU>
__global__ void gemm_kernel(const float* __restrict__ A,
                            const int* __restrict__ gidx,
                            const float* __restrict__ Bm,
                            const float* __restrict__ A2,
                            const float* __restrict__ B2,
                            const float* __restrict__ bias,
                            const float* __restrict__ res,
                            float* __restrict__ Cout,
                            int M, int K, int Nc) {
    __shared__ float As[16][64];
    __shared__ float Bs[16][64];
    int tid = threadIdx.x;
    int row0 = blockIdx.y * 64;
    int col0 = blockIdx.x * 64;
    int ty = tid >> 4;   // 0..15
    int tx = tid & 15;   // 0..15
    float acc[4][4] = {};

    int npass = (A2 != nullptr) ? 2 : 1;
    for (int pass = 0; pass < npass; ++pass) {
        const float* Ap = pass ? A2 : A;
        const float* Bp = pass ? B2 : Bm;
        for (int k0 = 0; k0 < K; k0 += 16) {
            // A tile: 64 rows x 16 cols
            {
                int r = tid >> 2;
                int c4 = (tid & 3) * 4;
                int ar = row0 + r;
                float4 val = make_float4(0.f, 0.f, 0.f, 0.f);
                if (ar < M) {
                    int arr = gidx ? gidx[ar] : ar;
                    val = *(const float4*)(Ap + (size_t)arr * K + k0 + c4);
                }
                As[c4 + 0][r] = val.x;
                As[c4 + 1][r] = val.y;
                As[c4 + 2][r] = val.z;
                As[c4 + 3][r] = val.w;
            }
            // B tile: 16 rows x 64 cols
            {
                int r = tid >> 4;
                int c4 = (tid & 15) * 4;
                *(float4*)&Bs[r][c4] = *(const float4*)(Bp + (size_t)(k0 + r) * Nc + col0 + c4);
            }
            __syncthreads();
#pragma unroll
            for (int kk = 0; kk < 16; ++kk) {
                float av[4], bv[4];
#pragma unroll
                for (int i = 0; i < 4; ++i) av[i] = As[kk][ty * 4 + i];
#pragma unroll
                for (int j = 0; j < 4; ++j) bv[j] = Bs[kk][tx * 4 + j];
#pragma unroll
                for (int i = 0; i < 4; ++i)
#pragma unroll
                    for (int j = 0; j < 4; ++j) acc[i][j] += av[i] * bv[j];
            }
            __syncthreads();
        }
    }

#pragma unroll
    for (int i = 0; i < 4; ++i) {
        int r = row0 + ty * 4 + i;
        if (r >= M) continue;
#pragma unroll
        for (int j = 0; j < 4; ++j) {
            int c = col0 + tx * 4 + j;
            float v = acc[i][j];
            if (bias) v += bias[c];
            if (res) v += res[(size_t)r * Nc + c];
            if (RELU) v = fmaxf(v, 0.f);
            Cout[(size_t)r * Nc + c] = v;
        }
    }
}

// ---------------------------------------------------------------------------
// Column stats (sum, sumsq) for BN over M rows x 256 cols
// ---------------------------------------------------------------------------
__global__ void colstats_kernel(const float* __restrict__ in,
                                float* __restrict__ stats, int M) {
    int c = threadIdx.x;  // 256
    int r0 = blockIdx.x * 64;
    int rend = min(r0 + 64, M);
    float s = 0.f, s2 = 0.f;
    for (int r = r0; r < rend; ++r) {
        float v = in[(size_t)r * Cc + c];
        s += v;
        s2 += v * v;
    }
    atomicAdd(&stats[c], s);
    atomicAdd(&stats[Cc + c], s2);
}

// ---------------------------------------------------------------------------
// BN apply: out = (add?) + g*(in-mean)*rsqrt(var+eps)+be
// ---------------------------------------------------------------------------
__global__ void bn_apply_kernel(const float* __restrict__ in,
                                float* __restrict__ out,
                                const float* __restrict__ add,
                                const float* __restrict__ g,
                                const float* __restrict__ be,
                                const float* __restrict__ stats, int M) {
    int gid = blockIdx.x * 256 + threadIdx.x;
    if (gid >= M * Cc) return;
    int c = gid & (Cc - 1);
    float invM = 1.f / (float)M;
    float mean = stats[c] * invM;
    float var = stats[Cc + c] * invM - mean * mean;
    float sc = g[c] * rsqrtf(var + EPS);
    float v = (in[gid] - mean) * sc + be[c];
    if (add) v += add[gid];
    out[gid] = v;
}

// ---------------------------------------------------------------------------
// Flash-style attention. One thread = one query row. grid = B*H*2, 256 thr.
// q,k,v layout: [B,T,H,Dh]; o layout: [B,T,C] with head-contiguous last dim.
// ---------------------------------------------------------------------------
__global__ void attn_kernel(const float* __restrict__ q,
                            const float* __restrict__ k,
                            const float* __restrict__ v,
                            const int* __restrict__ maskI,
                            float* __restrict__ o) {
    int bh = blockIdx.x >> 1;
    int qc = blockIdx.x & 1;
    int b = bh >> 3;
    int h = bh & 7;
    int qrow = qc * 256 + threadIdx.x;

    __shared__ float Ks[64][Dh];
    __shared__ float Vs[64][Dh];
    __shared__ int Ms[64];

    float qv[Dh];
    const float* qp = q + ((size_t)(b * Tc + qrow) * Hc + h) * Dh;
#pragma unroll
    for (int d = 0; d < Dh; d += 4) {
        float4 t = *(const float4*)(qp + d);
        qv[d] = t.x; qv[d + 1] = t.y; qv[d + 2] = t.z; qv[d + 3] = t.w;
    }

    float m = -1e30f, l = 0.f;
    float acc[Dh] = {};
    const float scale = 0.17677669529663687f;  // 1/sqrt(32)

    for (int k0 = 0; k0 < Tc; k0 += 64) {
        __syncthreads();
        {
            int r = threadIdx.x >> 2;
            int c8 = (threadIdx.x & 3) * 8;
            const float* kp = k + ((size_t)(b * Tc + k0 + r) * Hc + h) * Dh + c8;
            const float* vp = v + ((size_t)(b * Tc + k0 + r) * Hc + h) * Dh + c8;
            *(float4*)&Ks[r][c8] = *(const float4*)(kp);
            *(float4*)&Ks[r][c8 + 4] = *(const float4*)(kp + 4);
            *(float4*)&Vs[r][c8] = *(const float4*)(vp);
            *(float4*)&Vs[r][c8 + 4] = *(const float4*)(vp + 4);
            if (threadIdx.x < 64) Ms[threadIdx.x] = maskI[b * Tc + k0 + threadIdx.x];
        }
        __syncthreads();
        for (int j = 0; j < 64; ++j) {
            if (!Ms[j]) continue;  // uniform branch (same for all lanes)
            float s = 0.f;
#pragma unroll
            for (int d = 0; d < Dh; ++d) s += qv[d] * Ks[j][d];
            s *= scale;
            float mn = fmaxf(m, s);
            float corr = __expf(m - mn);
            float p = __expf(s - mn);
            l = l * corr + p;
#pragma unroll
            for (int d = 0; d < Dh; ++d) acc[d] = acc[d] * corr + p * Vs[j][d];
            m = mn;
        }
    }

    float inv = 1.f / l;
    float* op = o + (size_t)(b * Tc + qrow) * Cc + h * Dh;
#pragma unroll
    for (int d = 0; d < Dh; d += 4) {
        float4 t;
        t.x = acc[d] * inv; t.y = acc[d + 1] * inv;
        t.z = acc[d + 2] * inv; t.w = acc[d + 3] * inv;
        *(float4*)(op + d) = t;
    }
}

// ---------------------------------------------------------------------------
// Launch
// ---------------------------------------------------------------------------
extern "C" void kernel_launch(void* const* d_in, const int* in_sizes, int n_in,
                              void* d_out, int out_size, void* d_ws, size_t ws_size,
                              hipStream_t stream) {
    const float* x      = (const float*)d_in[0];
    const int*   ei     = (const int*)d_in[1];
    const int*   idx    = (const int*)d_in[2];
    // d_in[3] = mask (bool) — unused; reconstructed from idx
    const float* W_root = (const float*)d_in[4];
    const float* W_nbr  = (const float*)d_in[5];
    const float* b_conv = (const float*)d_in[6];
    const float* Wq     = (const float*)d_in[7];
    const float* Wk     = (const float*)d_in[8];
    const float* Wv     = (const float*)d_in[9];
    const float* bq     = (const float*)d_in[10];
    const float* bk     = (const float*)d_in[11];
    const float* bv     = (const float*)d_in[12];
    const float* Wo     = (const float*)d_in[13];
    const float* bo     = (const float*)d_in[14];
    const float* W1     = (const float*)d_in[15];
    const float* b1     = (const float*)d_in[16];
    const float* W2     = (const float*)d_in[17];
    const float* b2     = (const float*)d_in[18];
    const float* g1     = (const float*)d_in[19];
    const float* be1    = (const float*)d_in[20];
    const float* g2     = (const float*)d_in[21];
    const float* be2    = (const float*)d_in[22];
    const float* g3     = (const float*)d_in[23];
    const float* be3    = (const float*)d_in[24];

    const int N = in_sizes[0] / Cc;
    const int E = in_sizes[1] / 2;

    // Workspace layout (floats)
    float* ws = (float*)d_ws;
    float* hB    = ws;                       // N*C : h_pre -> h_local -> out1
    float* hid   = hB + (size_t)N * Cc;      // N*2C
    float* xd    = hid + (size_t)N * 2 * Cc; // BT*C
    float* qb    = xd + (size_t)BT * Cc;     // BT*C
    float* kb    = qb + (size_t)BT * Cc;     // BT*C
    float* vb    = kb + (size_t)BT * Cc;     // BT*C
    float* ao    = vb + (size_t)BT * Cc;     // BT*C attention out
    float* stats = ao + (size_t)BT * Cc;     // 6*C (3 sets of [sum, sumsq])
    int*   maskI = (int*)(stats + 6 * Cc);   // BT ints
    int*   deg    = maskI + BT;              // N
    int*   startA = deg + N;                 // N
    int*   cursor = startA + N;              // N
    int*   csr    = cursor + N;              // E
    // d_out doubles as a second N*C scratch: agg -> h_attn_pre -> out2 -> final
    float* bufA = (float*)d_out;

    // ---- zero the accumulated buffers ----
    hipMemsetAsync(xd, 0, (size_t)BT * Cc * sizeof(float), stream);
    hipMemsetAsync(stats, 0, 6 * Cc * sizeof(float), stream);
    hipMemsetAsync(maskI, 0, BT * sizeof(int), stream);
    hipMemsetAsync(deg, 0, N * sizeof(int), stream);
    hipMemsetAsync(cursor, 0, N * sizeof(int), stream);

    // ---- 1. agg = segment_sum(x[src], dst)  via CSR-gather (no float atomics)
    degree_kernel<<<(E + 255) / 256, 256, 0, stream>>>(ei, deg, E);
    prefix_kernel<<<1, 1024, 0, stream>>>(deg, startA, N);
    fill_csr_kernel<<<(E + 255) / 256, 256, 0, stream>>>(ei, startA, cursor, csr, E);
    gather_kernel<<<N, 256, 0, stream>>>(x, csr, startA, deg, bufA, N);

    // ---- 2. h_pre = x@W_root + agg@W_nbr + b_conv + x ----
    {
        dim3 grid(Cc / 64, (N + 63) / 64);
        gemm_kernel<false><<<grid, 256, 0, stream>>>(x, nullptr, W_root, bufA, W_nbr,
                                                     b_conv, x, hB, N, Cc, Cc);
    }
    // ---- 3. BN1 in place: hB = h_local ----
    colstats_kernel<<<(N + 63) / 64, 256, 0, stream>>>(hB, stats, N);
    bn_apply_kernel<<<N, 256, 0, stream>>>(hB, hB, nullptr, g1, be1, stats, N);

    // ---- 4. dense batch scatter + mask ----
    scatter_dense_kernel<<<(N * 64 + 255) / 256, 256, 0, stream>>>(x, idx, xd, maskI, N);

    // ---- 5. q,k,v = xd@W + b ----
    {
        dim3 grid(Cc / 64, BT / 64);
        gemm_kernel<false><<<grid, 256, 0, stream>>>(xd, nullptr, Wq, nullptr, nullptr,
                                                     bq, nullptr, qb, BT, Cc, Cc);
        gemm_kernel<false><<<grid, 256, 0, stream>>>(xd, nullptr, Wk, nullptr, nullptr,
                                                     bk, nullptr, kb, BT, Cc, Cc);
        gemm_kernel<false><<<grid, 256, 0, stream>>>(xd, nullptr, Wv, nullptr, nullptr,
                                                     bv, nullptr, vb, BT, Cc, Cc);
    }

    // ---- 6. attention -> ao [B,T,C] ----
    attn_kernel<<<Bc * Hc * 2, 256, 0, stream>>>(qb, kb, vb, maskI, ao);

    // ---- 7. h_attn_pre = ao[idx]@Wo + bo + x  (gathered unpad + residual) ----
    {
        dim3 grid(Cc / 64, (N + 63) / 64);
        gemm_kernel<false><<<grid, 256, 0, stream>>>(ao, idx, Wo, nullptr, nullptr,
                                                     bo, x, bufA, N, Cc, Cc);
    }
    // ---- 8. BN2 + combine: hB(out1) = h_local + bn(h_attn_pre) ----
    colstats_kernel<<<(N + 63) / 64, 256, 0, stream>>>(bufA, stats + 2 * Cc, N);
    bn_apply_kernel<<<N, 256, 0, stream>>>(bufA, hB, hB, g2, be2, stats + 2 * Cc, N);

    // ---- 9. hid = relu(out1@W1 + b1) ----
    {
        dim3 grid(2 * Cc / 64, (N + 63) / 64);
        gemm_kernel<true><<<grid, 256, 0, stream>>>(hB, nullptr, W1, nullptr, nullptr,
                                                    b1, nullptr, hid, N, Cc, 2 * Cc);
    }
    // ---- 10. out2 = out1 + hid@W2 + b2 ----
    {
        dim3 grid(Cc / 64, (N + 63) / 64);
        gemm_kernel<false><<<grid, 256, 0, stream>>>(hid, nullptr, W2, nullptr, nullptr,
                                                     b2, hB, bufA, N, 2 * Cc, Cc);
    }
    // ---- 11. BN3 -> d_out (in place on bufA == d_out) ----
    colstats_kernel<<<(N + 63) / 64, 256, 0, stream>>>(bufA, stats + 4 * Cc, N);
    bn_apply_kernel<<<N, 256, 0, stream>>>(bufA, bufA, nullptr, g3, be3, stats + 4 * Cc, N);
}

// Round 3
// 579.123 us; speedup vs baseline: 2.5084x; 1.3620x over previous
//
#include <hip/hip_runtime.h>
#include <hip/hip_bf16.h>
#include <math.h>

#define Bc 32
#define Tc 512
#define Cc 256
#define Hc 8
#define BT (Bc * Tc)
#define EPS 1e-5f
#define LDAP 40  // padded LDS row length in bf16 elems (80B, 16B-aligned, 2-way banks)

typedef __bf16 bf16x8 __attribute__((ext_vector_type(8)));
typedef float f32x4 __attribute__((ext_vector_type(4)));
typedef unsigned short us8_t __attribute__((ext_vector_type(8)));

__device__ inline unsigned short f2bf(float f) {
    unsigned int u = __float_as_uint(f);
    u += 0x7fffu + ((u >> 16) & 1u);   // RNE
    return (unsigned short)(u >> 16);
}

// ---------------------------------------------------------------------------
// Weight convert+transpose (f32 KxN -> bf16 NxK) for all weights, one launch.
// Layout in wsq (ushort elems):
//   [0,65536) Wr^T | [65536,131072) Wn^T | [131072,327680) Wqkv^T (768x256)
//   [327680,393216) Wo^T | [393216,524288) W1^T (512x256) | [524288,655360) W2^T (256x512)
// tail: bqkv concat (768 f32)
// ---------------------------------------------------------------------------
__global__ void wcvt_all_kernel(const float* __restrict__ Wr, const float* __restrict__ Wn,
                                const float* __restrict__ Wq, const float* __restrict__ Wk,
                                const float* __restrict__ Wv, const float* __restrict__ Wo,
                                const float* __restrict__ W1, const float* __restrict__ W2,
                                const float* __restrict__ bq, const float* __restrict__ bk,
                                const float* __restrict__ bv,
                                unsigned short* __restrict__ wsq, float* __restrict__ bqkv) {
    int gid = blockIdx.x * 256 + threadIdx.x;
    if (gid >= 656128) return;
    if (gid >= 655360) {
        int j = gid - 655360;
        bqkv[j] = (j < 256) ? bq[j] : (j < 512 ? bk[j - 256] : bv[j - 512]);
        return;
    }
    const float* src; int base, K, N;
    if (gid < 65536)       { src = Wr; base = 0;      K = 256; N = 256; }
    else if (gid < 131072) { src = Wn; base = 65536;  K = 256; N = 256; }
    else if (gid < 196608) { src = Wq; base = 131072; K = 256; N = 256; }
    else if (gid < 262144) { src = Wk; base = 196608; K = 256; N = 256; }
    else if (gid < 327680) { src = Wv; base = 262144; K = 256; N = 256; }
    else if (gid < 393216) { src = Wo; base = 327680; K = 256; N = 256; }
    else if (gid < 524288) { src = W1; base = 393216; K = 256; N = 512; }
    else                   { src = W2; base = 524288; K = 512; N = 256; }
    int loc = gid - base;
    int n = loc / K, k = loc % K;
    wsq[gid] = f2bf(src[(size_t)k * N + n]);
}

// ---------------------------------------------------------------------------
// CSR build + gather (segment_sum without float atomics)
// ---------------------------------------------------------------------------
__global__ void degree_kernel(const int* __restrict__ ei, int* __restrict__ deg, int E) {
    int e = blockIdx.x * 256 + threadIdx.x;
    if (e >= E) return;
    atomicAdd(&deg[ei[E + e]], 1);
}

__global__ void prefix_kernel(const int* __restrict__ deg, int* __restrict__ start, int N) {
    __shared__ int sums[1024];
    int tid = threadIdx.x;
    int per = (N + 1023) / 1024;
    int base = tid * per;
    int s = 0;
    for (int i = 0; i < per; ++i) {
        int g = base + i;
        if (g < N) s += deg[g];
    }
    sums[tid] = s;
    __syncthreads();
    for (int off = 1; off < 1024; off <<= 1) {
        int v = (tid >= off) ? sums[tid - off] : 0;
        __syncthreads();
        sums[tid] += v;
        __syncthreads();
    }
    int run = (tid == 0) ? 0 : sums[tid - 1];
    for (int i = 0; i < per; ++i) {
        int g = base + i;
        if (g < N) { start[g] = run; run += deg[g]; }
    }
}

__global__ void fill_csr_kernel(const int* __restrict__ ei, const int* __restrict__ start,
                                int* __restrict__ cursor, int* __restrict__ csr, int E) {
    int e = blockIdx.x * 256 + threadIdx.x;
    if (e >= E) return;
    int dst = ei[E + e];
    int pos = atomicAdd(&cursor[dst], 1);
    csr[start[dst] + pos] = ei[e];
}

__global__ void gather_kernel(const float* __restrict__ x, const int* __restrict__ csr,
                              const int* __restrict__ start, const int* __restrict__ deg,
                              float* __restrict__ agg, int N) {
    int i = blockIdx.x;
    int c = threadIdx.x;
    int s0 = start[i];
    int s1 = s0 + deg[i];
    float s = 0.f;
    for (int e = s0; e < s1; ++e)
        s += x[(size_t)csr[e] * Cc + c];
    agg[(size_t)i * Cc + c] = s;
}

// ---------------------------------------------------------------------------
// Dense-batch scatter + integer mask
// ---------------------------------------------------------------------------
__global__ void scatter_dense_kernel(const float* __restrict__ x, const int* __restrict__ idx,
                                     float* __restrict__ xd, int* __restrict__ maskI, int N) {
    int gid = blockIdx.x * 256 + threadIdx.x;
    int i = gid >> 6;
    if (i >= N) return;
    int c4 = (gid & 63) * 4;
    int slot = idx[i];
    *(float4*)(xd + (size_t)slot * Cc + c4) = *(const float4*)(x + (size_t)i * Cc + c4);
    if (c4 == 0) maskI[slot] = 1;
}

// ---------------------------------------------------------------------------
// bf16 MFMA GEMM: Cout(MxNc,f32) = act(A@Bt^T (+ A2@B2t^T) + bias (+ res))
//   A: MxK f32 (optional row gather), Bt: Nc x K bf16 (pre-transposed weights)
//   64x64 tile, BK=32, 4 waves (2x2), each wave 2x2 frags of 16x16x32
// ---------------------------------------------------------------------------
template <bool RELU>
__global__ __launch_bounds__(256) void gemm_mfma_kernel(
    const float* __restrict__ A, const int* __restrict__ gidx,
    const unsigned short* __restrict__ Bt,
    const float* __restrict__ A2, const unsigned short* __restrict__ B2t,
    const float* __restrict__ bias, const float* __restrict__ res,
    float* __restrict__ Cout, int M, int K, int Nc) {
    __shared__ unsigned short As[64 * LDAP];
    __shared__ unsigned short Bs[64 * LDAP];
    int tid = threadIdx.x;
    int row0 = blockIdx.y * 64;
    int col0 = blockIdx.x * 64;
    int lane = tid & 63;
    int w = tid >> 6;
    int wr = (w >> 1) * 32;
    int wc = (w & 1) * 32;

    f32x4 acc[2][2] = {};

    int npass = (A2 != nullptr) ? 2 : 1;
    for (int pass = 0; pass < npass; ++pass) {
        const float* Ap = pass ? A2 : A;
        const unsigned short* Bp = pass ? B2t : Bt;
        for (int k0 = 0; k0 < K; k0 += 32) {
            __syncthreads();
            {   // stage A: 64 rows x 32 k, f32 -> bf16
                int r = tid >> 2;
                int kc = (tid & 3) * 8;
                int ar = row0 + r;
                us8_t pk = {0, 0, 0, 0, 0, 0, 0, 0};
                if (ar < M) {
                    int arr = gidx ? gidx[ar] : ar;
                    const float* srcp = Ap + (size_t)arr * K + k0 + kc;
                    float4 f0 = *(const float4*)(srcp);
                    float4 f1 = *(const float4*)(srcp + 4);
                    pk[0] = f2bf(f0.x); pk[1] = f2bf(f0.y);
                    pk[2] = f2bf(f0.z); pk[3] = f2bf(f0.w);
                    pk[4] = f2bf(f1.x); pk[5] = f2bf(f1.y);
                    pk[6] = f2bf(f1.z); pk[7] = f2bf(f1.w);
                }
                *(us8_t*)&As[r * LDAP + kc] = pk;
            }
            {   // stage B: 64 cols x 32 k (already bf16, row-major in k)
                int c = tid >> 2;
                int kc = (tid & 3) * 8;
                *(us8_t*)&Bs[c * LDAP + kc] =
                    *(const us8_t*)(Bp + (size_t)(col0 + c) * K + k0 + kc);
            }
            __syncthreads();
            int fr = lane & 15;
            int kk = (lane >> 4) * 8;
            bf16x8 af0 = *(bf16x8*)&As[(wr + fr) * LDAP + kk];
            bf16x8 af1 = *(bf16x8*)&As[(wr + 16 + fr) * LDAP + kk];
            bf16x8 bf0 = *(bf16x8*)&Bs[(wc + fr) * LDAP + kk];
            bf16x8 bf1 = *(bf16x8*)&Bs[(wc + 16 + fr) * LDAP + kk];
            acc[0][0] = __builtin_amdgcn_mfma_f32_16x16x32_bf16(af0, bf0, acc[0][0], 0, 0, 0);
            acc[0][1] = __builtin_amdgcn_mfma_f32_16x16x32_bf16(af0, bf1, acc[0][1], 0, 0, 0);
            acc[1][0] = __builtin_amdgcn_mfma_f32_16x16x32_bf16(af1, bf0, acc[1][0], 0, 0, 0);
            acc[1][1] = __builtin_amdgcn_mfma_f32_16x16x32_bf16(af1, bf1, acc[1][1], 0, 0, 0);
        }
    }
    // epilogue: C/D layout col=lane&15, row=(lane>>4)*4+reg
    int fr = lane & 15;
    int rq = (lane >> 4) * 4;
#pragma unroll
    for (int fm = 0; fm < 2; ++fm) {
#pragma unroll
        for (int fn = 0; fn < 2; ++fn) {
            int col = col0 + wc + fn * 16 + fr;
#pragma unroll
            for (int i = 0; i < 4; ++i) {
                int row = row0 + wr + fm * 16 + rq + i;
                if (row < M) {
                    float v = acc[fm][fn][i];
                    if (bias) v += bias[col];
                    if (res) v += res[(size_t)row * Nc + col];
                    if (RELU) v = fmaxf(v, 0.f);
                    Cout[(size_t)row * Nc + col] = v;
                }
            }
        }
    }
}

// ---------------------------------------------------------------------------
// Column stats + BN apply
// ---------------------------------------------------------------------------
__global__ void colstats_kernel(const float* __restrict__ in, float* __restrict__ stats, int M) {
    int c = threadIdx.x;
    int r0 = blockIdx.x * 64;
    int rend = min(r0 + 64, M);
    float s = 0.f, s2 = 0.f;
    for (int r = r0; r < rend; ++r) {
        float v = in[(size_t)r * Cc + c];
        s += v;
        s2 += v * v;
    }
    atomicAdd(&stats[c], s);
    atomicAdd(&stats[Cc + c], s2);
}

__global__ void bn_apply_kernel(const float* __restrict__ in, float* __restrict__ out,
                                const float* __restrict__ add, const float* __restrict__ g,
                                const float* __restrict__ be, const float* __restrict__ stats,
                                int M) {
    int gid = blockIdx.x * 256 + threadIdx.x;
    if (gid >= M * Cc) return;
    int c = gid & (Cc - 1);
    float invM = 1.f / (float)M;
    float mean = stats[c] * invM;
    float var = stats[Cc + c] * invM - mean * mean;
    float sc = g[c] * rsqrtf(var + EPS);
    float v = (in[gid] - mean) * sc + be[c];
    if (add) v += add[gid];
    out[gid] = v;
}

// ---------------------------------------------------------------------------
// Flash attention, thread-per-query, chunked rescale (16 keys per rescale).
// qkv: [BT][768] fused (q|k|v, head-contig 32); o: [BT][256].
// ---------------------------------------------------------------------------
__global__ __launch_bounds__(256) void attn_kernel(const float* __restrict__ qkv,
                                                   const int* __restrict__ maskI,
                                                   float* __restrict__ o) {
    int bh = blockIdx.x >> 1;
    int qc = blockIdx.x & 1;
    int b = bh >> 3;
    int h = bh & 7;
    int qrow = qc * 256 + (int)threadIdx.x;

    __shared__ float Ks[64][36];
    __shared__ float Vs[64][36];
    __shared__ int Ms[64];

    float qv[32];
    const float* qp = qkv + (size_t)(b * Tc + qrow) * 768 + h * 32;
#pragma unroll
    for (int d = 0; d < 32; d += 4) {
        float4 t = *(const float4*)(qp + d);
        qv[d] = t.x; qv[d + 1] = t.y; qv[d + 2] = t.z; qv[d + 3] = t.w;
    }

    float m = -1e30f, l = 0.f;
    float acc[32] = {};
    const float scale = 0.17677669529663687f;

    for (int k0 = 0; k0 < Tc; k0 += 64) {
        __syncthreads();
        {
            int r = threadIdx.x >> 2;
            int c8 = (threadIdx.x & 3) * 8;
            const float* kp = qkv + (size_t)(b * Tc + k0 + r) * 768 + 256 + h * 32 + c8;
            const float* vp = kp + 256;
            *(float4*)&Ks[r][c8] = *(const float4*)(kp);
            *(float4*)&Ks[r][c8 + 4] = *(const float4*)(kp + 4);
            *(float4*)&Vs[r][c8] = *(const float4*)(vp);
            *(float4*)&Vs[r][c8 + 4] = *(const float4*)(vp + 4);
            if (threadIdx.x < 64) Ms[threadIdx.x] = maskI[b * Tc + k0 + threadIdx.x];
        }
        __syncthreads();
#pragma unroll 1
        for (int jj = 0; jj < 4; ++jj) {
            if (!Ms[jj * 16]) continue;  // prefix mask: rest of group empty (uniform)
            float s16[16];
            float cmax = -1e30f;
#pragma unroll
            for (int i = 0; i < 16; ++i) {
                int j = jj * 16 + i;
                float t = 0.f;
#pragma unroll
                for (int d = 0; d < 32; d += 4) {
                    float4 kv = *(const float4*)&Ks[j][d];
                    t += qv[d] * kv.x + qv[d + 1] * kv.y + qv[d + 2] * kv.z + qv[d + 3] * kv.w;
                }
                t *= scale;
                t = Ms[j] ? t : -1e30f;
                s16[i] = t;
                cmax = fmaxf(cmax, t);
            }
            float mn = fmaxf(m, cmax);
            float corr = __expf(m - mn);
            l *= corr;
#pragma unroll
            for (int d = 0; d < 32; ++d) acc[d] *= corr;
#pragma unroll
            for (int i = 0; i < 16; ++i) {
                float p = __expf(s16[i] - mn);
                l += p;
                int j = jj * 16 + i;
#pragma unroll
                for (int d = 0; d < 32; d += 4) {
                    float4 vv = *(const float4*)&Vs[j][d];
                    acc[d] += p * vv.x;
                    acc[d + 1] += p * vv.y;
                    acc[d + 2] += p * vv.z;
                    acc[d + 3] += p * vv.w;
                }
            }
            m = mn;
        }
    }

    float inv = 1.f / l;
    float* op = o + (size_t)(b * Tc + qrow) * Cc + h * 32;
#pragma unroll
    for (int d = 0; d < 32; d += 4) {
        float4 t;
        t.x = acc[d] * inv; t.y = acc[d + 1] * inv;
        t.z = acc[d + 2] * inv; t.w = acc[d + 3] * inv;
        *(float4*)(op + d) = t;
    }
}

// ---------------------------------------------------------------------------
// Launch
// ---------------------------------------------------------------------------
extern "C" void kernel_launch(void* const* d_in, const int* in_sizes, int n_in,
                              void* d_out, int out_size, void* d_ws, size_t ws_size,
                              hipStream_t stream) {
    const float* x      = (const float*)d_in[0];
    const int*   ei     = (const int*)d_in[1];
    const int*   idx    = (const int*)d_in[2];
    const float* W_root = (const float*)d_in[4];
    const float* W_nbr  = (const float*)d_in[5];
    const float* b_conv = (const float*)d_in[6];
    const float* Wq     = (const float*)d_in[7];
    const float* Wk     = (const float*)d_in[8];
    const float* Wv     = (const float*)d_in[9];
    const float* bq     = (const float*)d_in[10];
    const float* bk     = (const float*)d_in[11];
    const float* bv     = (const float*)d_in[12];
    const float* Wo     = (const float*)d_in[13];
    const float* bo     = (const float*)d_in[14];
    const float* W1     = (const float*)d_in[15];
    const float* b1     = (const float*)d_in[16];
    const float* W2     = (const float*)d_in[17];
    const float* b2     = (const float*)d_in[18];
    const float* g1     = (const float*)d_in[19];
    const float* be1    = (const float*)d_in[20];
    const float* g2     = (const float*)d_in[21];
    const float* be2    = (const float*)d_in[22];
    const float* g3     = (const float*)d_in[23];
    const float* be3    = (const float*)d_in[24];

    const int N = in_sizes[0] / Cc;
    const int E = in_sizes[1] / 2;

    // Workspace layout (floats)
    float* ws = (float*)d_ws;
    float* hB    = ws;                        // N*C   (h_local -> out1)
    float* hid   = hB + (size_t)N * Cc;       // N*2C
    float* xd    = hid + (size_t)N * 2 * Cc;  // BT*C  (dense x; later reused as attn out)
    float* qkv   = xd + (size_t)BT * Cc;      // BT*768
    float* stats = qkv + (size_t)BT * 768;    // 6*C
    float* bqkv  = stats + 6 * Cc;            // 768
    unsigned short* wsq = (unsigned short*)(bqkv + 768);  // 655360 bf16
    int* maskI  = (int*)(wsq + 655360);       // BT
    int* deg    = maskI + BT;                 // N
    int* startA = deg + N;                    // N
    int* cursor = startA + N;                 // N
    int* csr    = cursor + N;                 // E
    float* bufA = (float*)d_out;              // N*C scratch: agg -> h_attn_pre -> out2 -> final
    float* ao = xd;                           // attention output overwrites xd

    const unsigned short* Wrt   = wsq;
    const unsigned short* Wnt   = wsq + 65536;
    const unsigned short* Wqkvt = wsq + 131072;
    const unsigned short* Wot   = wsq + 327680;
    const unsigned short* W1t   = wsq + 393216;
    const unsigned short* W2t   = wsq + 524288;

    hipMemsetAsync(xd, 0, (size_t)BT * Cc * sizeof(float), stream);
    hipMemsetAsync(stats, 0, 6 * Cc * sizeof(float), stream);
    hipMemsetAsync(maskI, 0, BT * sizeof(int), stream);
    hipMemsetAsync(deg, 0, N * sizeof(int), stream);
    hipMemsetAsync(cursor, 0, N * sizeof(int), stream);

    // ---- 0. weights -> bf16 transposed; bias concat ----
    wcvt_all_kernel<<<(656128 + 255) / 256, 256, 0, stream>>>(
        W_root, W_nbr, Wq, Wk, Wv, Wo, W1, W2, bq, bk, bv, wsq, bqkv);

    // ---- 1. agg = segment_sum(x[src], dst) via CSR gather ----
    degree_kernel<<<(E + 255) / 256, 256, 0, stream>>>(ei, deg, E);
    prefix_kernel<<<1, 1024, 0, stream>>>(deg, startA, N);
    fill_csr_kernel<<<(E + 255) / 256, 256, 0, stream>>>(ei, startA, cursor, csr, E);
    gather_kernel<<<N, 256, 0, stream>>>(x, csr, startA, deg, bufA, N);

    // ---- 2. h_pre = x@W_root + agg@W_nbr + b_conv + x ----
    {
        dim3 grid(Cc / 64, (N + 63) / 64);
        gemm_mfma_kernel<false><<<grid, 256, 0, stream>>>(
            x, nullptr, Wrt, bufA, Wnt, b_conv, x, hB, N, Cc, Cc);
    }
    // ---- 3. BN1 in place ----
    colstats_kernel<<<(N + 63) / 64, 256, 0, stream>>>(hB, stats, N);
    bn_apply_kernel<<<N, 256, 0, stream>>>(hB, hB, nullptr, g1, be1, stats, N);

    // ---- 4. dense scatter + mask ----
    scatter_dense_kernel<<<(N * 64 + 255) / 256, 256, 0, stream>>>(x, idx, xd, maskI, N);

    // ---- 5. fused QKV GEMM: qkv = xd @ [Wq|Wk|Wv] + [bq|bk|bv] ----
    {
        dim3 grid(768 / 64, BT / 64);
        gemm_mfma_kernel<false><<<grid, 256, 0, stream>>>(
            xd, nullptr, Wqkvt, nullptr, nullptr, bqkv, nullptr, qkv, BT, Cc, 768);
    }

    // ---- 6. attention -> ao (reuses xd) ----
    attn_kernel<<<Bc * Hc * 2, 256, 0, stream>>>(qkv, maskI, ao);

    // ---- 7. h_attn_pre = ao[idx]@Wo + bo + x ----
    {
        dim3 grid(Cc / 64, (N + 63) / 64);
        gemm_mfma_kernel<false><<<grid, 256, 0, stream>>>(
            ao, idx, Wot, nullptr, nullptr, bo, x, bufA, N, Cc, Cc);
    }
    // ---- 8. out1 = h_local + bn(h_attn_pre) ----
    colstats_kernel<<<(N + 63) / 64, 256, 0, stream>>>(bufA, stats + 2 * Cc, N);
    bn_apply_kernel<<<N, 256, 0, stream>>>(bufA, hB, hB, g2, be2, stats + 2 * Cc, N);

    // ---- 9. hid = relu(out1@W1 + b1) ----
    {
        dim3 grid(512 / 64, (N + 63) / 64);
        gemm_mfma_kernel<true><<<grid, 256, 0, stream>>>(
            hB, nullptr, W1t, nullptr, nullptr, b1, nullptr, hid, N, Cc, 512);
    }
    // ---- 10. out2 = out1 + hid@W2 + b2 ----
    {
        dim3 grid(Cc / 64, (N + 63) / 64);
        gemm_mfma_kernel<false><<<grid, 256, 0, stream>>>(
            hid, nullptr, W2t, nullptr, nullptr, b2, hB, bufA, N, 512, Cc);
    }
    // ---- 11. BN3 -> d_out ----
    colstats_kernel<<<(N + 63) / 64, 256, 0, stream>>>(bufA, stats + 4 * Cc, N);
    bn_apply_kernel<<<N, 256, 0, stream>>>(bufA, bufA, nullptr, g3, be3, stats + 4 * Cc, N);
}

// Round 4
// 423.616 us; speedup vs baseline: 3.4293x; 1.3671x over previous
//
#include <hip/hip_runtime.h>
#include <hip/hip_bf16.h>
#include <math.h>

#define Bc 32
#define Tc 512
#define Cc 256
#define Hc 8
#define BT (Bc * Tc)
#define EPS 1e-5f
#define LDAP 40  // padded LDS row length in bf16 elems (80B, 16B-aligned, 2-way banks)

typedef __bf16 bf16x8 __attribute__((ext_vector_type(8)));
typedef float f32x4 __attribute__((ext_vector_type(4)));
typedef unsigned short us8_t __attribute__((ext_vector_type(8)));

__device__ inline unsigned short f2bf(float f) {
    unsigned int u = __float_as_uint(f);
    u += 0x7fffu + ((u >> 16) & 1u);   // RNE
    return (unsigned short)(u >> 16);
}

// ---------------------------------------------------------------------------
// Weight convert+transpose (f32 KxN -> bf16 NxK) for all weights, one launch.
// ---------------------------------------------------------------------------
__global__ void wcvt_all_kernel(const float* __restrict__ Wr, const float* __restrict__ Wn,
                                const float* __restrict__ Wq, const float* __restrict__ Wk,
                                const float* __restrict__ Wv, const float* __restrict__ Wo,
                                const float* __restrict__ W1, const float* __restrict__ W2,
                                const float* __restrict__ bq, const float* __restrict__ bk,
                                const float* __restrict__ bv,
                                unsigned short* __restrict__ wsq, float* __restrict__ bqkv) {
    int gid = blockIdx.x * 256 + threadIdx.x;
    if (gid >= 656128) return;
    if (gid >= 655360) {
        int j = gid - 655360;
        bqkv[j] = (j < 256) ? bq[j] : (j < 512 ? bk[j - 256] : bv[j - 512]);
        return;
    }
    const float* src; int base, K, N;
    if (gid < 65536)       { src = Wr; base = 0;      K = 256; N = 256; }
    else if (gid < 131072) { src = Wn; base = 65536;  K = 256; N = 256; }
    else if (gid < 196608) { src = Wq; base = 131072; K = 256; N = 256; }
    else if (gid < 262144) { src = Wk; base = 196608; K = 256; N = 256; }
    else if (gid < 327680) { src = Wv; base = 262144; K = 256; N = 256; }
    else if (gid < 393216) { src = Wo; base = 327680; K = 256; N = 256; }
    else if (gid < 524288) { src = W1; base = 393216; K = 256; N = 512; }
    else                   { src = W2; base = 524288; K = 512; N = 256; }
    int loc = gid - base;
    int n = loc / K, k = loc % K;
    wsq[gid] = f2bf(src[(size_t)k * N + n]);
}

// ---------------------------------------------------------------------------
// CSR build + gather (segment_sum without float atomics)
// ---------------------------------------------------------------------------
__global__ void degree_kernel(const int* __restrict__ ei, int* __restrict__ deg, int E) {
    int e = blockIdx.x * 256 + threadIdx.x;
    if (e >= E) return;
    atomicAdd(&deg[ei[E + e]], 1);
}

__global__ void prefix_kernel(const int* __restrict__ deg, int* __restrict__ start, int N) {
    __shared__ int sums[1024];
    int tid = threadIdx.x;
    int per = (N + 1023) / 1024;
    int base = tid * per;
    int s = 0;
    for (int i = 0; i < per; ++i) {
        int g = base + i;
        if (g < N) s += deg[g];
    }
    sums[tid] = s;
    __syncthreads();
    for (int off = 1; off < 1024; off <<= 1) {
        int v = (tid >= off) ? sums[tid - off] : 0;
        __syncthreads();
        sums[tid] += v;
        __syncthreads();
    }
    int run = (tid == 0) ? 0 : sums[tid - 1];
    for (int i = 0; i < per; ++i) {
        int g = base + i;
        if (g < N) { start[g] = run; run += deg[g]; }
    }
}

__global__ void fill_csr_kernel(const int* __restrict__ ei, const int* __restrict__ start,
                                int* __restrict__ cursor, int* __restrict__ csr, int E) {
    int e = blockIdx.x * 256 + threadIdx.x;
    if (e >= E) return;
    int dst = ei[E + e];
    int pos = atomicAdd(&cursor[dst], 1);
    csr[start[dst] + pos] = ei[e];
}

__global__ void gather_kernel(const float* __restrict__ x, const int* __restrict__ csr,
                              const int* __restrict__ start, const int* __restrict__ deg,
                              float* __restrict__ agg, int N) {
    int i = blockIdx.x;
    int c = threadIdx.x;
    int s0 = start[i];
    int s1 = s0 + deg[i];
    float s = 0.f;
    for (int e = s0; e < s1; ++e)
        s += x[(size_t)csr[e] * Cc + c];
    agg[(size_t)i * Cc + c] = s;
}

// ---------------------------------------------------------------------------
// Dense-batch scatter + integer mask
// ---------------------------------------------------------------------------
__global__ void scatter_dense_kernel(const float* __restrict__ x, const int* __restrict__ idx,
                                     float* __restrict__ xd, int* __restrict__ maskI, int N) {
    int gid = blockIdx.x * 256 + threadIdx.x;
    int i = gid >> 6;
    if (i >= N) return;
    int c4 = (gid & 63) * 4;
    int slot = idx[i];
    *(float4*)(xd + (size_t)slot * Cc + c4) = *(const float4*)(x + (size_t)i * Cc + c4);
    if (c4 == 0) maskI[slot] = 1;
}

// ---------------------------------------------------------------------------
// bf16 MFMA GEMM (unchanged from R3)
// ---------------------------------------------------------------------------
template <bool RELU>
__global__ __launch_bounds__(256) void gemm_mfma_kernel(
    const float* __restrict__ A, const int* __restrict__ gidx,
    const unsigned short* __restrict__ Bt,
    const float* __restrict__ A2, const unsigned short* __restrict__ B2t,
    const float* __restrict__ bias, const float* __restrict__ res,
    float* __restrict__ Cout, int M, int K, int Nc) {
    __shared__ unsigned short As[64 * LDAP];
    __shared__ unsigned short Bs[64 * LDAP];
    int tid = threadIdx.x;
    int row0 = blockIdx.y * 64;
    int col0 = blockIdx.x * 64;
    int lane = tid & 63;
    int w = tid >> 6;
    int wr = (w >> 1) * 32;
    int wc = (w & 1) * 32;

    f32x4 acc[2][2] = {};

    int npass = (A2 != nullptr) ? 2 : 1;
    for (int pass = 0; pass < npass; ++pass) {
        const float* Ap = pass ? A2 : A;
        const unsigned short* Bp = pass ? B2t : Bt;
        for (int k0 = 0; k0 < K; k0 += 32) {
            __syncthreads();
            {   // stage A: 64 rows x 32 k, f32 -> bf16
                int r = tid >> 2;
                int kc = (tid & 3) * 8;
                int ar = row0 + r;
                us8_t pk = {0, 0, 0, 0, 0, 0, 0, 0};
                if (ar < M) {
                    int arr = gidx ? gidx[ar] : ar;
                    const float* srcp = Ap + (size_t)arr * K + k0 + kc;
                    float4 f0 = *(const float4*)(srcp);
                    float4 f1 = *(const float4*)(srcp + 4);
                    pk[0] = f2bf(f0.x); pk[1] = f2bf(f0.y);
                    pk[2] = f2bf(f0.z); pk[3] = f2bf(f0.w);
                    pk[4] = f2bf(f1.x); pk[5] = f2bf(f1.y);
                    pk[6] = f2bf(f1.z); pk[7] = f2bf(f1.w);
                }
                *(us8_t*)&As[r * LDAP + kc] = pk;
            }
            {   // stage B
                int c = tid >> 2;
                int kc = (tid & 3) * 8;
                *(us8_t*)&Bs[c * LDAP + kc] =
                    *(const us8_t*)(Bp + (size_t)(col0 + c) * K + k0 + kc);
            }
            __syncthreads();
            int fr = lane & 15;
            int kk = (lane >> 4) * 8;
            bf16x8 af0 = *(bf16x8*)&As[(wr + fr) * LDAP + kk];
            bf16x8 af1 = *(bf16x8*)&As[(wr + 16 + fr) * LDAP + kk];
            bf16x8 bf0 = *(bf16x8*)&Bs[(wc + fr) * LDAP + kk];
            bf16x8 bf1 = *(bf16x8*)&Bs[(wc + 16 + fr) * LDAP + kk];
            acc[0][0] = __builtin_amdgcn_mfma_f32_16x16x32_bf16(af0, bf0, acc[0][0], 0, 0, 0);
            acc[0][1] = __builtin_amdgcn_mfma_f32_16x16x32_bf16(af0, bf1, acc[0][1], 0, 0, 0);
            acc[1][0] = __builtin_amdgcn_mfma_f32_16x16x32_bf16(af1, bf0, acc[1][0], 0, 0, 0);
            acc[1][1] = __builtin_amdgcn_mfma_f32_16x16x32_bf16(af1, bf1, acc[1][1], 0, 0, 0);
        }
    }
    int fr = lane & 15;
    int rq = (lane >> 4) * 4;
#pragma unroll
    for (int fm = 0; fm < 2; ++fm) {
#pragma unroll
        for (int fn = 0; fn < 2; ++fn) {
            int col = col0 + wc + fn * 16 + fr;
#pragma unroll
            for (int i = 0; i < 4; ++i) {
                int row = row0 + wr + fm * 16 + rq + i;
                if (row < M) {
                    float v = acc[fm][fn][i];
                    if (bias) v += bias[col];
                    if (res) v += res[(size_t)row * Nc + col];
                    if (RELU) v = fmaxf(v, 0.f);
                    Cout[(size_t)row * Nc + col] = v;
                }
            }
        }
    }
}

// ---------------------------------------------------------------------------
// Column stats + BN apply
// ---------------------------------------------------------------------------
__global__ void colstats_kernel(const float* __restrict__ in, float* __restrict__ stats, int M) {
    int c = threadIdx.x;
    int r0 = blockIdx.x * 64;
    int rend = min(r0 + 64, M);
    float s = 0.f, s2 = 0.f;
    for (int r = r0; r < rend; ++r) {
        float v = in[(size_t)r * Cc + c];
        s += v;
        s2 += v * v;
    }
    atomicAdd(&stats[c], s);
    atomicAdd(&stats[Cc + c], s2);
}

__global__ void bn_apply_kernel(const float* __restrict__ in, float* __restrict__ out,
                                const float* __restrict__ add, const float* __restrict__ g,
                                const float* __restrict__ be, const float* __restrict__ stats,
                                int M) {
    int gid = blockIdx.x * 256 + threadIdx.x;
    if (gid >= M * Cc) return;
    int c = gid & (Cc - 1);
    float invM = 1.f / (float)M;
    float mean = stats[c] * invM;
    float var = stats[Cc + c] * invM - mean * mean;
    float sc = g[c] * rsqrtf(var + EPS);
    float v = (in[gid] - mean) * sc + be[c];
    if (add) v += add[gid];
    out[gid] = v;
}

// ---------------------------------------------------------------------------
// MFMA flash attention.
// Grid: b*64 + h*8 + qt (2048 blocks), 256 threads = 4 waves.
// Wave w handles q-rows [qt*64 + w*16, +16) of (b,h).
// qkv: [BT][768] (q|k|v, head-contig 32). o: [BT][256].
// ---------------------------------------------------------------------------
__global__ __launch_bounds__(256) void attn_mfma_kernel(const float* __restrict__ qkv,
                                                        const int* __restrict__ maskI,
                                                        float* __restrict__ o) {
    const int blk = blockIdx.x;
    const int qt = blk & 7;
    const int bh = blk >> 3;
    const int b = bh >> 3;
    const int h = bh & 7;
    const int tid = threadIdx.x;
    const int lane = tid & 63;
    const int w = tid >> 6;
    const int fr = lane & 15;
    const int g = lane >> 4;
    const int kk = g * 8;
    const int q0 = qt * 64 + w * 16;

    __shared__ unsigned short Ks[32 * LDAP];      // [key][dim]
    __shared__ unsigned short Vt[32 * LDAP];      // [dim][key]
    __shared__ unsigned short Pl[4][16 * LDAP];   // per-wave P [q_local][key]
    __shared__ int cnt_s;

    // ---- count valid keys for this batch (prefix mask) ----
    if (tid == 0) cnt_s = 0;
    __syncthreads();
    {
        int v = 0;
        for (int i = tid; i < Tc; i += 256) v += maskI[b * Tc + i];
        v += __shfl_xor(v, 1);  v += __shfl_xor(v, 2);  v += __shfl_xor(v, 4);
        v += __shfl_xor(v, 8);  v += __shfl_xor(v, 16); v += __shfl_xor(v, 32);
        if (lane == 0) atomicAdd(&cnt_s, v);
    }
    __syncthreads();
    const int count = cnt_s;

    // ---- load Q fragment (scale folded in): row=fr -> q0+fr, k=kk..kk+8 ----
    const float scale = 0.17677669529663687f;  // 1/sqrt(32)
    bf16x8 qa;
    {
        const float* qp = qkv + (size_t)(b * Tc + q0 + fr) * 768 + h * 32 + kk;
        float4 f0 = *(const float4*)(qp);
        float4 f1 = *(const float4*)(qp + 4);
        unsigned short u[8];
        u[0] = f2bf(f0.x * scale); u[1] = f2bf(f0.y * scale);
        u[2] = f2bf(f0.z * scale); u[3] = f2bf(f0.w * scale);
        u[4] = f2bf(f1.x * scale); u[5] = f2bf(f1.y * scale);
        u[6] = f2bf(f1.z * scale); u[7] = f2bf(f1.w * scale);
        qa = *(bf16x8*)u;
    }

    f32x4 opv0 = {0.f, 0.f, 0.f, 0.f};
    f32x4 opv1 = {0.f, 0.f, 0.f, 0.f};
    float l_part[4] = {0.f, 0.f, 0.f, 0.f};
    float mrow[4] = {-1e30f, -1e30f, -1e30f, -1e30f};

    const int nt = (count + 31) >> 5;
    for (int t = 0; t < nt; ++t) {
        const int kbase = t * 32;
        __syncthreads();
        {   // stage K [32][40] and V^T [32][40]
            int key = tid >> 3;
            int d4 = (tid & 7) * 4;
            const float* kp = qkv + (size_t)(b * Tc + kbase + key) * 768 + 256 + h * 32 + d4;
            float4 kf = *(const float4*)kp;
            ushort4 kw;
            kw.x = f2bf(kf.x); kw.y = f2bf(kf.y); kw.z = f2bf(kf.z); kw.w = f2bf(kf.w);
            *(ushort4*)&Ks[key * LDAP + d4] = kw;
            float4 vf = *(const float4*)(kp + 256);
            Vt[(d4 + 0) * LDAP + key] = f2bf(vf.x);
            Vt[(d4 + 1) * LDAP + key] = f2bf(vf.y);
            Vt[(d4 + 2) * LDAP + key] = f2bf(vf.z);
            Vt[(d4 + 3) * LDAP + key] = f2bf(vf.w);
        }
        __syncthreads();

        // ---- S = Q @ K^T : two 16-key fragments ----
        bf16x8 kb0 = *(bf16x8*)&Ks[fr * LDAP + kk];
        bf16x8 kb1 = *(bf16x8*)&Ks[(16 + fr) * LDAP + kk];
        f32x4 z = {0.f, 0.f, 0.f, 0.f};
        f32x4 s0 = __builtin_amdgcn_mfma_f32_16x16x32_bf16(qa, kb0, z, 0, 0, 0);
        f32x4 s1 = __builtin_amdgcn_mfma_f32_16x16x32_bf16(qa, kb1, z, 0, 0, 0);

        // ---- mask (prefix): this lane's key columns ----
        const bool v0 = (kbase + fr) < count;
        const bool v1 = (kbase + 16 + fr) < count;
#pragma unroll
        for (int i = 0; i < 4; ++i) {
            s0[i] = v0 ? s0[i] : -1e30f;
            s1[i] = v1 ? s1[i] : -1e30f;
        }

        // ---- row max over the 16 fr-lanes ----
        float rmax[4];
#pragma unroll
        for (int i = 0; i < 4; ++i) rmax[i] = fmaxf(s0[i], s1[i]);
#pragma unroll
        for (int i = 0; i < 4; ++i) {
            rmax[i] = fmaxf(rmax[i], __shfl_xor(rmax[i], 1));
            rmax[i] = fmaxf(rmax[i], __shfl_xor(rmax[i], 2));
            rmax[i] = fmaxf(rmax[i], __shfl_xor(rmax[i], 4));
            rmax[i] = fmaxf(rmax[i], __shfl_xor(rmax[i], 8));
        }

        // ---- online rescale ----
        float p0[4], p1[4];
#pragma unroll
        for (int i = 0; i < 4; ++i) {
            float mn = fmaxf(mrow[i], rmax[i]);
            float corr = __expf(mrow[i] - mn);
            mrow[i] = mn;
            l_part[i] *= corr;
            opv0[i] *= corr;
            opv1[i] *= corr;
            p0[i] = __expf(s0[i] - mn);
            p1[i] = __expf(s1[i] - mn);
            l_part[i] += p0[i] + p1[i];
        }

        // ---- P -> own-wave LDS slab (bf16), then PV ----
        unsigned short* pw = &Pl[w][0];
#pragma unroll
        for (int i = 0; i < 4; ++i) {
            pw[(g * 4 + i) * LDAP + fr] = f2bf(p0[i]);
            pw[(g * 4 + i) * LDAP + 16 + fr] = f2bf(p1[i]);
        }
        // same-wave LDS write->read: keep program order, LDS pipe is in-order per wave
        asm volatile("s_waitcnt lgkmcnt(0)" ::: "memory");

        bf16x8 pa = *(bf16x8*)&pw[fr * LDAP + kk];          // A: row=q_local, k=key
        bf16x8 vb0 = *(bf16x8*)&Vt[fr * LDAP + kk];         // B: col=d, k=key
        bf16x8 vb1 = *(bf16x8*)&Vt[(16 + fr) * LDAP + kk];
        opv0 = __builtin_amdgcn_mfma_f32_16x16x32_bf16(pa, vb0, opv0, 0, 0, 0);
        opv1 = __builtin_amdgcn_mfma_f32_16x16x32_bf16(pa, vb1, opv1, 0, 0, 0);
    }

    // ---- final l reduction over fr-lanes, normalize, store ----
#pragma unroll
    for (int i = 0; i < 4; ++i) {
        l_part[i] += __shfl_xor(l_part[i], 1);
        l_part[i] += __shfl_xor(l_part[i], 2);
        l_part[i] += __shfl_xor(l_part[i], 4);
        l_part[i] += __shfl_xor(l_part[i], 8);
    }
#pragma unroll
    for (int i = 0; i < 4; ++i) {
        float inv = 1.f / l_part[i];
        size_t row = (size_t)(b * Tc + q0 + g * 4 + i);
        o[row * Cc + h * 32 + fr] = opv0[i] * inv;
        o[row * Cc + h * 32 + 16 + fr] = opv1[i] * inv;
    }
}

// ---------------------------------------------------------------------------
// Launch
// ---------------------------------------------------------------------------
extern "C" void kernel_launch(void* const* d_in, const int* in_sizes, int n_in,
                              void* d_out, int out_size, void* d_ws, size_t ws_size,
                              hipStream_t stream) {
    const float* x      = (const float*)d_in[0];
    const int*   ei     = (const int*)d_in[1];
    const int*   idx    = (const int*)d_in[2];
    const float* W_root = (const float*)d_in[4];
    const float* W_nbr  = (const float*)d_in[5];
    const float* b_conv = (const float*)d_in[6];
    const float* Wq     = (const float*)d_in[7];
    const float* Wk     = (const float*)d_in[8];
    const float* Wv     = (const float*)d_in[9];
    const float* bq     = (const float*)d_in[10];
    const float* bk     = (const float*)d_in[11];
    const float* bv     = (const float*)d_in[12];
    const float* Wo     = (const float*)d_in[13];
    const float* bo     = (const float*)d_in[14];
    const float* W1     = (const float*)d_in[15];
    const float* b1     = (const float*)d_in[16];
    const float* W2     = (const float*)d_in[17];
    const float* b2     = (const float*)d_in[18];
    const float* g1     = (const float*)d_in[19];
    const float* be1    = (const float*)d_in[20];
    const float* g2     = (const float*)d_in[21];
    const float* be2    = (const float*)d_in[22];
    const float* g3     = (const float*)d_in[23];
    const float* be3    = (const float*)d_in[24];

    const int N = in_sizes[0] / Cc;
    const int E = in_sizes[1] / 2;

    float* ws = (float*)d_ws;
    float* hB    = ws;                        // N*C
    float* hid   = hB + (size_t)N * Cc;       // N*2C
    float* xd    = hid + (size_t)N * 2 * Cc;  // BT*C (dense x; reused as attn out)
    float* qkv   = xd + (size_t)BT * Cc;      // BT*768
    float* stats = qkv + (size_t)BT * 768;    // 6*C
    float* bqkv  = stats + 6 * Cc;            // 768
    unsigned short* wsq = (unsigned short*)(bqkv + 768);  // 655360 bf16
    int* maskI  = (int*)(wsq + 655360);       // BT
    int* deg    = maskI + BT;                 // N
    int* startA = deg + N;                    // N
    int* cursor = startA + N;                 // N
    int* csr    = cursor + N;                 // E
    float* bufA = (float*)d_out;              // N*C scratch
    float* ao = xd;

    const unsigned short* Wrt   = wsq;
    const unsigned short* Wnt   = wsq + 65536;
    const unsigned short* Wqkvt = wsq + 131072;
    const unsigned short* Wot   = wsq + 327680;
    const unsigned short* W1t   = wsq + 393216;
    const unsigned short* W2t   = wsq + 524288;

    hipMemsetAsync(xd, 0, (size_t)BT * Cc * sizeof(float), stream);
    hipMemsetAsync(stats, 0, 6 * Cc * sizeof(float), stream);
    hipMemsetAsync(maskI, 0, BT * sizeof(int), stream);
    hipMemsetAsync(deg, 0, N * sizeof(int), stream);
    hipMemsetAsync(cursor, 0, N * sizeof(int), stream);

    wcvt_all_kernel<<<(656128 + 255) / 256, 256, 0, stream>>>(
        W_root, W_nbr, Wq, Wk, Wv, Wo, W1, W2, bq, bk, bv, wsq, bqkv);

    degree_kernel<<<(E + 255) / 256, 256, 0, stream>>>(ei, deg, E);
    prefix_kernel<<<1, 1024, 0, stream>>>(deg, startA, N);
    fill_csr_kernel<<<(E + 255) / 256, 256, 0, stream>>>(ei, startA, cursor, csr, E);
    gather_kernel<<<N, 256, 0, stream>>>(x, csr, startA, deg, bufA, N);

    {
        dim3 grid(Cc / 64, (N + 63) / 64);
        gemm_mfma_kernel<false><<<grid, 256, 0, stream>>>(
            x, nullptr, Wrt, bufA, Wnt, b_conv, x, hB, N, Cc, Cc);
    }
    colstats_kernel<<<(N + 63) / 64, 256, 0, stream>>>(hB, stats, N);
    bn_apply_kernel<<<N, 256, 0, stream>>>(hB, hB, nullptr, g1, be1, stats, N);

    scatter_dense_kernel<<<(N * 64 + 255) / 256, 256, 0, stream>>>(x, idx, xd, maskI, N);

    {
        dim3 grid(768 / 64, BT / 64);
        gemm_mfma_kernel<false><<<grid, 256, 0, stream>>>(
            xd, nullptr, Wqkvt, nullptr, nullptr, bqkv, nullptr, qkv, BT, Cc, 768);
    }

    attn_mfma_kernel<<<Bc * Hc * 8, 256, 0, stream>>>(qkv, maskI, ao);

    {
        dim3 grid(Cc / 64, (N + 63) / 64);
        gemm_mfma_kernel<false><<<grid, 256, 0, stream>>>(
            ao, idx, Wot, nullptr, nullptr, bo, x, bufA, N, Cc, Cc);
    }
    colstats_kernel<<<(N + 63) / 64, 256, 0, stream>>>(bufA, stats + 2 * Cc, N);
    bn_apply_kernel<<<N, 256, 0, stream>>>(bufA, hB, hB, g2, be2, stats + 2 * Cc, N);

    {
        dim3 grid(512 / 64, (N + 63) / 64);
        gemm_mfma_kernel<true><<<grid, 256, 0, stream>>>(
            hB, nullptr, W1t, nullptr, nullptr, b1, nullptr, hid, N, Cc, 512);
    }
    {
        dim3 grid(Cc / 64, (N + 63) / 64);
        gemm_mfma_kernel<false><<<grid, 256, 0, stream>>>(
            hid, nullptr, W2t, nullptr, nullptr, b2, hB, bufA, N, 512, Cc);
    }
    colstats_kernel<<<(N + 63) / 64, 256, 0, stream>>>(bufA, stats + 4 * Cc, N);
    bn_apply_kernel<<<N, 256, 0, stream>>>(bufA, bufA, nullptr, g3, be3, stats + 4 * Cc, N);
}